// Round 3
// baseline (596.520 us; speedup 1.0000x reference)
//
#include <hip/hip_runtime.h>

typedef unsigned short u16;
typedef __attribute__((ext_vector_type(8))) short short8;
typedef __attribute__((ext_vector_type(4))) float floatx4;

#define NN_TOT 135168   // 4096 * 33

// ---- compile-time skeleton (from SKELETON_EDGES, incl. self-loops) ----
static constexpr int NBCNT[33] = {2,2,2,2,2,2,2,1,1,1,1,3,3,2,2,4,4,2,2,2,2,1,1,3,3,2,2,3,3,2,2,2,2};
static constexpr int NBR[33][4] = {
 {1,4,0,0},{0,2,0,0},{1,3,0,0},{2,7,0,0},{0,5,0,0},{4,6,0,0},{5,8,0,0},
 {3,0,0,0},{6,0,0,0},{10,0,0,0},{9,0,0,0},
 {12,13,23,0},{11,14,24,0},{11,15,0,0},{12,16,0,0},
 {13,17,19,21},{14,18,20,22},
 {15,19,0,0},{16,20,0,0},{15,17,0,0},{16,18,0,0},{15,0,0,0},{16,0,0,0},
 {11,24,25,0},{12,23,26,0},{23,27,0,0},{24,28,0,0},
 {25,29,31,0},{26,30,32,0},{27,31,0,0},{28,32,0,0},{29,27,0,0},{30,28,0,0}};
static constexpr float R2 = 0.70710678f, R3 = 0.57735027f, R4 = 0.5f, R5 = 0.44721360f;
static constexpr float DINV[33] = {R3,R3,R3,R3,R3,R3,R3, R2,R2,R2,R2, R4,R4, R3,R3, R5,R5,
                                   R3,R3,R3,R3, R2,R2, R4,R4, R3,R3, R4,R4, R3,R3,R3,R3};

__device__ __forceinline__ float bf2f(u16 u) {
  unsigned int v = ((unsigned int)u) << 16; float f; __builtin_memcpy(&f, &v, 4); return f;
}
__device__ __forceinline__ u16 f2bf(float f) {
  unsigned int u; __builtin_memcpy(&u, &f, 4);
  return (u16)((u + 0x7fffu + ((u >> 16) & 1u)) >> 16);
}
// dtype-flexible input read: isbf ? bf16[i] : f32[i]
__device__ __forceinline__ float ldin(const void* p, int i, int isbf) {
  return isbf ? bf2f(((const u16*)p)[i]) : ((const float*)p)[i];
}

// ---- dtype detector (unchanged) ----
__global__ __launch_bounds__(256) void detect_kernel(const u16* __restrict__ x,
                                                     int* __restrict__ flag)
{
  __shared__ int cnt[256];
  const int t = threadIdx.x;
  int c = 0;
  for (int j = 0; j < 16; ++j) {
    u16 u = x[(t*16 + j)*2];
    int e = (u >> 7) & 0xFF;
    c += (e >= 118 && e <= 130) ? 1 : 0;
  }
  cnt[t] = c;
  __syncthreads();
  if (t == 0) {
    int s = 0;
    for (int i = 0; i < 256; ++i) s += cnt[i];
    *flag = (s > 2048) ? 1 : 0;   // 1 = bf16 inputs, 0 = fp32 inputs
  }
}

// ---- W transpose + canonicalize to bf16: Wt[n][k] = W[k][n] ----
__global__ __launch_bounds__(256) void transpose_kernel(const void* __restrict__ w0,
    const void* __restrict__ w1, const void* __restrict__ w2, u16* __restrict__ Wt,
    const int* __restrict__ flag)
{
  const int m = blockIdx.x >> 4;
  const int nb = (blockIdx.x & 15) * 16;
  const void* W = m == 0 ? w0 : (m == 1 ? w1 : w2);
  u16* O = Wt + (size_t)m * 65536;
  const int t = threadIdx.x;
  const int lane = t & 63, wv = t >> 6;
  const int isbf = *flag;
  if (isbf) {
    const u16* Wb = (const u16*)W;
#pragma unroll
    for (int nn = 0; nn < 4; ++nn) {
      const int n = nb + nn*4 + wv;
#pragma unroll
      for (int j = 0; j < 4; ++j) {
        const int k = lane + 64*j;
        O[n*256 + k] = Wb[k*256 + n];
      }
    }
  } else {
    const float* Wf = (const float*)W;
#pragma unroll
    for (int nn = 0; nn < 4; ++nn) {
      const int n = nb + nn*4 + wv;
#pragma unroll
      for (int j = 0; j < 4; ++j) {
        const int k = lane + 64*j;
        O[n*256 + k] = f2bf(Wf[k*256 + n]);
      }
    }
  }
}

// ---- init: wq = wh@wc, bq = bh@wc + bc, zero stat replicas ----
__global__ __launch_bounds__(256) void init_kernel(const void* __restrict__ wh,
    const void* __restrict__ bh, const void* __restrict__ wc, const void* __restrict__ bc,
    float* __restrict__ wq, float* __restrict__ bq, float* __restrict__ repl,
    const int* __restrict__ flag)
{
  const int idx = blockIdx.x*256 + threadIdx.x;
  for (int i = idx; i < 3*64*512; i += 65*256) repl[i] = 0.f;
  const int isbf = *flag;
  const int t = threadIdx.x;
  const int lane = t & 63;
  if (blockIdx.x < 64) {
    const int r = blockIdx.x*4 + (t >> 6);    // wq row, one per wave
    float a0=0.f, a1=0.f, a2=0.f, a3=0.f;
#pragma unroll
    for (int j = 0; j < 4; ++j) {
      const int k = lane + 64*j;
      const float w = ldin(wh, r*256 + k, isbf);
      a0 += w*ldin(wc, k*4+0, isbf); a1 += w*ldin(wc, k*4+1, isbf);
      a2 += w*ldin(wc, k*4+2, isbf); a3 += w*ldin(wc, k*4+3, isbf);
    }
#pragma unroll
    for (int off = 32; off; off >>= 1) {
      a0 += __shfl_xor(a0, off); a1 += __shfl_xor(a1, off);
      a2 += __shfl_xor(a2, off); a3 += __shfl_xor(a3, off);
    }
    if (lane == 0) { wq[r*4+0]=a0; wq[r*4+1]=a1; wq[r*4+2]=a2; wq[r*4+3]=a3; }
  } else if (t < 64) {
    float s0=0.f, s1=0.f, s2=0.f, s3=0.f;
#pragma unroll
    for (int j = 0; j < 4; ++j) {
      const int k = lane + 64*j;
      const float b = ldin(bh, k, isbf);
      s0 += b*ldin(wc, k*4+0, isbf); s1 += b*ldin(wc, k*4+1, isbf);
      s2 += b*ldin(wc, k*4+2, isbf); s3 += b*ldin(wc, k*4+3, isbf);
    }
#pragma unroll
    for (int off = 32; off; off >>= 1) {
      s0 += __shfl_xor(s0, off); s1 += __shfl_xor(s1, off);
      s2 += __shfl_xor(s2, off); s3 += __shfl_xor(s3, off);
    }
    if (lane == 0) {
      bq[0] = s0 + ldin(bc, 0, isbf); bq[1] = s1 + ldin(bc, 1, isbf);
      bq[2] = s2 + ldin(bc, 2, isbf); bq[3] = s3 + ldin(bc, 3, isbf);
    }
  }
}

// ---- MFMA GEMM: T = act(Ag) @ W   (M=135168, N=K=256) ----
// ZERO-LDS / ZERO-BARRIER structure: both MFMA fragments are 16B-contiguous
// in row-major memory, so A and B frags load DIRECTLY from global (dwordx4
// per lane). B panel (128 KB) is L2/L1-hot; waves run free (no syncthreads
// at all), so load latency hides under MFMA + TLP without any pipelining.
// Block = 128 rows x full N=256 (in-place safe: block reads/writes only its
// own 128-row stripe). Wave owns 32 rows; acc = 2 mg x 16 nf x 4 = 128 regs.
// ACT==0: identity, Ag = external x (dtype per flag), out-of-place -> T
// ACT==1: BN-ReLU scale/shift applied in registers, bf16 in/out, IN-PLACE.
template<int ACT>
__global__ __launch_bounds__(256, 2) void gemm_kernel(
    const void* __restrict__ Ag, const u16* __restrict__ Bt,
    const float* __restrict__ fscale, const float* __restrict__ fshift,
    u16* __restrict__ T, const int* __restrict__ flag)
{
  const int tid = threadIdx.x;
  const int lane = tid & 63, w = tid >> 6;
  const int fr = lane & 15, q = lane >> 4;
  const size_t m0 = (size_t)blockIdx.x * 128;
  const int rbase = w * 32;                 // wave's 32-row stripe in block
  const int isbf = (ACT == 0) ? *flag : 1;

  const u16* Ab = (const u16*)Ag;
  const float* Af = (const float*)Ag;

  floatx4 acc[2][16];
#pragma unroll
  for (int i = 0; i < 2; ++i)
#pragma unroll
    for (int j = 0; j < 16; ++j) acc[i][j] = (floatx4){0.f, 0.f, 0.f, 0.f};

  for (int kc = 0; kc < 8; ++kc) {
    const int k0 = kc * 32;

    // ---- A fragments (2 mgroups), direct from global, act applied in regs
    short8 a[2];
    if (ACT == 0) {
      if (isbf) {
#pragma unroll
        for (int mg = 0; mg < 2; ++mg)
          a[mg] = *(const short8*)(Ab + (m0 + rbase + mg*16 + fr)*256 + k0 + q*8);
      } else {
#pragma unroll
        for (int mg = 0; mg < 2; ++mg) {
          const float* ap = Af + (m0 + rbase + mg*16 + fr)*256 + k0 + q*8;
          float4 p0 = *(const float4*)(ap);
          float4 p1 = *(const float4*)(ap + 4);
          u16 ov[8];
          ov[0]=f2bf(p0.x); ov[1]=f2bf(p0.y); ov[2]=f2bf(p0.z); ov[3]=f2bf(p0.w);
          ov[4]=f2bf(p1.x); ov[5]=f2bf(p1.y); ov[6]=f2bf(p1.z); ov[7]=f2bf(p1.w);
          a[mg] = *(const short8*)ov;
        }
      }
    } else {
      float4 sc0 = *(const float4*)(fscale + k0 + q*8);
      float4 sc1 = *(const float4*)(fscale + k0 + q*8 + 4);
      float4 sh0 = *(const float4*)(fshift + k0 + q*8);
      float4 sh1 = *(const float4*)(fshift + k0 + q*8 + 4);
      const float scv[8] = {sc0.x,sc0.y,sc0.z,sc0.w, sc1.x,sc1.y,sc1.z,sc1.w};
      const float shv[8] = {sh0.x,sh0.y,sh0.z,sh0.w, sh1.x,sh1.y,sh1.z,sh1.w};
#pragma unroll
      for (int mg = 0; mg < 2; ++mg) {
        uint4 pk = *(const uint4*)(Ab + (m0 + rbase + mg*16 + fr)*256 + k0 + q*8);
        const u16* us = (const u16*)&pk;
        u16 ov[8];
#pragma unroll
        for (int j = 0; j < 8; ++j) {
          float f = bf2f(us[j]);
          f = fmaxf(0.f, fmaf(f, scv[j], shv[j]));
          ov[j] = f2bf(f);
        }
        a[mg] = *(const short8*)ov;
      }
    }

    // ---- B fragments direct from global (L1/L2-hot 128 KB panel), two
    // halves of 8 to bound register pressure
#pragma unroll
    for (int h = 0; h < 2; ++h) {
      short8 b[8];
#pragma unroll
      for (int nf = 0; nf < 8; ++nf)
        b[nf] = *(const short8*)(Bt + (h*128 + nf*16 + fr)*256 + k0 + q*8);
#pragma unroll
      for (int mg = 0; mg < 2; ++mg)
#pragma unroll
        for (int nf = 0; nf < 8; ++nf)
          acc[mg][h*8 + nf] =
            __builtin_amdgcn_mfma_f32_16x16x32_bf16(a[mg], b[nf], acc[mg][h*8 + nf], 0, 0, 0);
    }
  }

  // ---- epilogue: direct scalar stores (16 lanes x 2B = full 32B sectors;
  // r1-proven exact WRITE_SIZE). ~128 wave-instrs/wave — issue-trivial.
#pragma unroll
  for (int mg = 0; mg < 2; ++mg)
#pragma unroll
    for (int n = 0; n < 16; ++n)
#pragma unroll
      for (int r = 0; r < 4; ++r) {
        const size_t row = m0 + rbase + mg*16 + q*4 + r;
        T[row*256 + n*16 + fr] = f2bf(acc[mg][n][r]);
      }
}

// ---- per-graph aggregation H = Ahat @ T + b (IN-PLACE: H == T), BN stats ----
__global__ __launch_bounds__(256) void agg_kernel(const u16* __restrict__ T,
    const void* __restrict__ bias, u16* __restrict__ H, float* __restrict__ repl,
    const int* __restrict__ flag)
{
  const int g = blockIdx.x, c = threadIdx.x;
  const int isbf = *flag;
  const u16* tg = T + (size_t)g * (33*256);
  u16* hg = H + (size_t)g * (33*256);
  float acc[33];
#pragma unroll
  for (int d = 0; d < 33; ++d) acc[d] = 0.f;
#pragma unroll
  for (int s = 0; s < 33; ++s) {
    float v = bf2f(tg[s*256 + c]) * DINV[s];
    acc[s] += v;                          // self loop
#pragma unroll
    for (int i = 0; i < NBCNT[s]; ++i) acc[NBR[s][i]] += v;
  }
  const float bv = ldin(bias, c, isbf);
  float s1 = 0.f, s2 = 0.f;
#pragma unroll
  for (int d = 0; d < 33; ++d) {
    float o = fmaf(acc[d], DINV[d], bv);
    hg[d*256 + c] = f2bf(o);
    s1 += o; s2 += o*o;
  }
  float* r1 = repl + (size_t)(g & 63) * 512;
  atomicAdd(r1 + c, s1);
  atomicAdd(r1 + 256 + c, s2);
}

// ---- finalize BN stats -> scale/shift ----
__global__ __launch_bounds__(256) void statfin_kernel(const float* __restrict__ repl,
    const void* __restrict__ gamma, const void* __restrict__ beta, float* __restrict__ fs,
    const int* __restrict__ flag)
{
  const int c = threadIdx.x;
  const int isbf = *flag;
  float s1 = 0.f, s2 = 0.f;
  for (int r = 0; r < 64; ++r) { s1 += repl[r*512 + c]; s2 += repl[r*512 + 256 + c]; }
  const float inv = 1.f / (float)NN_TOT;
  const float mu = s1 * inv;
  const float var = s2 * inv - mu*mu;
  const float rs = rsqrtf(var + 1e-5f);
  const float sc = rs * ldin(gamma, c, isbf);
  fs[c] = sc;
  fs[256 + c] = ldin(beta, c, isbf) - mu * sc;
}

// ---- fused layer3 + mean-pool + classifier ----
__global__ __launch_bounds__(256) void final_kernel(const u16* __restrict__ H,
    const float* __restrict__ fs, const float* __restrict__ wq,
    const float* __restrict__ bq, void* __restrict__ outp,
    const int* __restrict__ flag)
{
  const int g = blockIdx.x, c = threadIdx.x;
  const int isbf = *flag;
  const float sc = fs[c], sh = fs[256 + c];
  const u16* hg = H + (size_t)g * (33*256);
  float v = 0.f;
#pragma unroll
  for (int s = 0; s < 33; ++s) {
    float a = DINV[s];
#pragma unroll
    for (int i = 0; i < NBCNT[s]; ++i) a += DINV[NBR[s][i]];
    const float w = DINV[s] * a * (1.f/33.f);   // column-sum of Ahat / 33
    float x = bf2f(hg[s*256 + c]);
    x = fmaxf(0.f, fmaf(x, sc, sh));
    v += w * x;
  }
  float p0 = v*wq[c*4+0], p1 = v*wq[c*4+1], p2 = v*wq[c*4+2], p3 = v*wq[c*4+3];
#pragma unroll
  for (int off = 32; off; off >>= 1) {
    p0 += __shfl_xor(p0, off);
    p1 += __shfl_xor(p1, off);
    p2 += __shfl_xor(p2, off);
    p3 += __shfl_xor(p3, off);
  }
  __shared__ float sred[4][4];
  const int lane = c & 63, wid = c >> 6;
  if (lane == 0) { sred[wid][0]=p0; sred[wid][1]=p1; sred[wid][2]=p2; sred[wid][3]=p3; }
  __syncthreads();
  if (c < 4) {
    float r = sred[0][c] + sred[1][c] + sred[2][c] + sred[3][c] + bq[c];
    if (isbf) ((u16*)outp)[(size_t)g*4 + c] = f2bf(r);
    else      ((float*)outp)[(size_t)g*4 + c] = r;
  }
}

extern "C" void kernel_launch(void* const* d_in, const int* in_sizes, int n_in,
                              void* d_out, int out_size, void* d_ws, size_t ws_size,
                              hipStream_t stream)
{
  const void* x   = d_in[0];
  const void* w0  = d_in[1];
  const void* b0  = d_in[2];
  const void* g0  = d_in[3];
  const void* be0 = d_in[4];
  const void* w1  = d_in[5];
  const void* b1  = d_in[6];
  const void* g1  = d_in[7];
  const void* be1 = d_in[8];
  const void* w2  = d_in[9];
  const void* b2  = d_in[10];
  const void* g2  = d_in[11];
  const void* be2 = d_in[12];
  const void* wh  = d_in[13];
  const void* bh  = d_in[14];
  const void* wc  = d_in[15];
  const void* bc  = d_in[16];

  // Workspace: 66.8 MB total.
  char* ws = (char*)d_ws;
  float* wq   = (float*)(ws + 0);          // 1024 f
  float* bq   = (float*)(ws + 4096);       // 4 f
  float* fs   = (float*)(ws + 4608);       // 3 * 512 f
  int*   flag = (int*)  (ws + 12288);      // dtype flag
  float* repl = (float*)(ws + 16384);      // 3 * 64 * 512 f
  u16*   Wt   = (u16*)  (ws + 409600);     // 3 * 65536 bf16
  u16*   A    = (u16*)  (ws + 802816);     // 135168*256 bf16 (ends at 70,008,832)
  (void)in_sizes; (void)n_in; (void)out_size; (void)ws_size;

  detect_kernel<<<1, 256, 0, stream>>>((const u16*)x, flag);
  transpose_kernel<<<48, 256, 0, stream>>>(w0, w1, w2, Wt, flag);
  init_kernel<<<65, 256, 0, stream>>>(wh, bh, wc, bc, wq, bq, repl, flag);

  // layer 0
  gemm_kernel<0><<<1056, 256, 0, stream>>>(x, Wt, nullptr, nullptr, A, flag);
  agg_kernel<<<4096, 256, 0, stream>>>(A, b0, A, repl, flag);
  statfin_kernel<<<1, 256, 0, stream>>>(repl, g0, be0, fs, flag);
  // layer 1 (in-place GEMM)
  gemm_kernel<1><<<1056, 256, 0, stream>>>(A, Wt + 65536, fs, fs + 256, A, flag);
  agg_kernel<<<4096, 256, 0, stream>>>(A, b1, A, repl + 32768, flag);
  statfin_kernel<<<1, 256, 0, stream>>>(repl + 32768, g1, be1, fs + 512, flag);
  // layer 2 (in-place GEMM)
  gemm_kernel<1><<<1056, 256, 0, stream>>>(A, Wt + 131072, fs + 512, fs + 768, A, flag);
  agg_kernel<<<4096, 256, 0, stream>>>(A, b2, A, repl + 65536, flag);
  statfin_kernel<<<1, 256, 0, stream>>>(repl + 65536, g2, be2, fs + 1024, flag);
  // layer 3 + pool + classifier (folded)
  final_kernel<<<4096, 256, 0, stream>>>(A, fs + 1024, wq, bq, d_out, flag);
}

// Round 4
// 448.301 us; speedup vs baseline: 1.3306x; 1.3306x over previous
//
#include <hip/hip_runtime.h>

typedef unsigned short u16;
typedef __attribute__((ext_vector_type(8))) short short8;
typedef __attribute__((ext_vector_type(4))) float floatx4;

#define NN_TOT 135168   // 4096 * 33

// ---- compile-time skeleton (from SKELETON_EDGES, incl. self-loops) ----
static constexpr int NBCNT[33] = {2,2,2,2,2,2,2,1,1,1,1,3,3,2,2,4,4,2,2,2,2,1,1,3,3,2,2,3,3,2,2,2,2};
static constexpr int NBR[33][4] = {
 {1,4,0,0},{0,2,0,0},{1,3,0,0},{2,7,0,0},{0,5,0,0},{4,6,0,0},{5,8,0,0},
 {3,0,0,0},{6,0,0,0},{10,0,0,0},{9,0,0,0},
 {12,13,23,0},{11,14,24,0},{11,15,0,0},{12,16,0,0},
 {13,17,19,21},{14,18,20,22},
 {15,19,0,0},{16,20,0,0},{15,17,0,0},{16,18,0,0},{15,0,0,0},{16,0,0,0},
 {11,24,25,0},{12,23,26,0},{23,27,0,0},{24,28,0,0},
 {25,29,31,0},{26,30,32,0},{27,31,0,0},{28,32,0,0},{29,27,0,0},{30,28,0,0}};
static constexpr float R2 = 0.70710678f, R3 = 0.57735027f, R4 = 0.5f, R5 = 0.44721360f;
static constexpr float DINV[33] = {R3,R3,R3,R3,R3,R3,R3, R2,R2,R2,R2, R4,R4, R3,R3, R5,R5,
                                   R3,R3,R3,R3, R2,R2, R4,R4, R3,R3, R4,R4, R3,R3,R3,R3};

__device__ __forceinline__ float bf2f(u16 u) {
  unsigned int v = ((unsigned int)u) << 16; float f; __builtin_memcpy(&f, &v, 4); return f;
}
__device__ __forceinline__ u16 f2bf(float f) {
  unsigned int u; __builtin_memcpy(&u, &f, 4);
  return (u16)((u + 0x7fffu + ((u >> 16) & 1u)) >> 16);
}
// dtype-flexible input read: isbf ? bf16[i] : f32[i]
__device__ __forceinline__ float ldin(const void* p, int i, int isbf) {
  return isbf ? bf2f(((const u16*)p)[i]) : ((const float*)p)[i];
}
__device__ __forceinline__ void gload_lds16(const u16* g, u16* l) {
  __builtin_amdgcn_global_load_lds((const __attribute__((address_space(1))) unsigned int*)g,
                                   (__attribute__((address_space(3))) unsigned int*)l, 16, 0, 0);
}

// ---- dtype detector (unchanged) ----
__global__ __launch_bounds__(256) void detect_kernel(const u16* __restrict__ x,
                                                     int* __restrict__ flag)
{
  __shared__ int cnt[256];
  const int t = threadIdx.x;
  int c = 0;
  for (int j = 0; j < 16; ++j) {
    u16 u = x[(t*16 + j)*2];
    int e = (u >> 7) & 0xFF;
    c += (e >= 118 && e <= 130) ? 1 : 0;
  }
  cnt[t] = c;
  __syncthreads();
  if (t == 0) {
    int s = 0;
    for (int i = 0; i < 256; ++i) s += cnt[i];
    *flag = (s > 2048) ? 1 : 0;   // 1 = bf16 inputs, 0 = fp32 inputs
  }
}

// ---- W transpose + canonicalize to bf16: Wt[n][k] = W[k][n] ----
__global__ __launch_bounds__(256) void transpose_kernel(const void* __restrict__ w0,
    const void* __restrict__ w1, const void* __restrict__ w2, u16* __restrict__ Wt,
    const int* __restrict__ flag)
{
  const int m = blockIdx.x >> 4;
  const int nb = (blockIdx.x & 15) * 16;
  const void* W = m == 0 ? w0 : (m == 1 ? w1 : w2);
  u16* O = Wt + (size_t)m * 65536;
  const int t = threadIdx.x;
  const int lane = t & 63, wv = t >> 6;
  const int isbf = *flag;
  if (isbf) {
    const u16* Wb = (const u16*)W;
#pragma unroll
    for (int nn = 0; nn < 4; ++nn) {
      const int n = nb + nn*4 + wv;
#pragma unroll
      for (int j = 0; j < 4; ++j) {
        const int k = lane + 64*j;
        O[n*256 + k] = Wb[k*256 + n];
      }
    }
  } else {
    const float* Wf = (const float*)W;
#pragma unroll
    for (int nn = 0; nn < 4; ++nn) {
      const int n = nb + nn*4 + wv;
#pragma unroll
      for (int j = 0; j < 4; ++j) {
        const int k = lane + 64*j;
        O[n*256 + k] = f2bf(Wf[k*256 + n]);
      }
    }
  }
}

// ---- init: wq = wh@wc, bq = bh@wc + bc, zero stat replicas ----
__global__ __launch_bounds__(256) void init_kernel(const void* __restrict__ wh,
    const void* __restrict__ bh, const void* __restrict__ wc, const void* __restrict__ bc,
    float* __restrict__ wq, float* __restrict__ bq, float* __restrict__ repl,
    const int* __restrict__ flag)
{
  const int idx = blockIdx.x*256 + threadIdx.x;
  for (int i = idx; i < 3*64*512; i += 65*256) repl[i] = 0.f;
  const int isbf = *flag;
  const int t = threadIdx.x;
  const int lane = t & 63;
  if (blockIdx.x < 64) {
    const int r = blockIdx.x*4 + (t >> 6);    // wq row, one per wave
    float a0=0.f, a1=0.f, a2=0.f, a3=0.f;
#pragma unroll
    for (int j = 0; j < 4; ++j) {
      const int k = lane + 64*j;
      const float w = ldin(wh, r*256 + k, isbf);
      a0 += w*ldin(wc, k*4+0, isbf); a1 += w*ldin(wc, k*4+1, isbf);
      a2 += w*ldin(wc, k*4+2, isbf); a3 += w*ldin(wc, k*4+3, isbf);
    }
#pragma unroll
    for (int off = 32; off; off >>= 1) {
      a0 += __shfl_xor(a0, off); a1 += __shfl_xor(a1, off);
      a2 += __shfl_xor(a2, off); a3 += __shfl_xor(a3, off);
    }
    if (lane == 0) { wq[r*4+0]=a0; wq[r*4+1]=a1; wq[r*4+2]=a2; wq[r*4+3]=a3; }
  } else if (t < 64) {
    float s0=0.f, s1=0.f, s2=0.f, s3=0.f;
#pragma unroll
    for (int j = 0; j < 4; ++j) {
      const int k = lane + 64*j;
      const float b = ldin(bh, k, isbf);
      s0 += b*ldin(wc, k*4+0, isbf); s1 += b*ldin(wc, k*4+1, isbf);
      s2 += b*ldin(wc, k*4+2, isbf); s3 += b*ldin(wc, k*4+3, isbf);
    }
#pragma unroll
    for (int off = 32; off; off >>= 1) {
      s0 += __shfl_xor(s0, off); s1 += __shfl_xor(s1, off);
      s2 += __shfl_xor(s2, off); s3 += __shfl_xor(s3, off);
    }
    if (lane == 0) {
      bq[0] = s0 + ldin(bc, 0, isbf); bq[1] = s1 + ldin(bc, 1, isbf);
      bq[2] = s2 + ldin(bc, 2, isbf); bq[3] = s3 + ldin(bc, 3, isbf);
    }
  }
}

// ---- FUSED layer: H = Ahat @ (act(Ag) @ W) + b, plus BN stats ----
// Block = 256 threads = 4 waves = 2 graphs (66 rows), grid 2048 (2048*66 = NN_TOT).
// Wave w: graph gi = w>>1 (rows gi*33..+32), col-half h = w&1 (cols h*128..+127).
// M covered by 3 tiles of 16 (48 rows); rows >=33 read stale LDS, masked at output
// => zero extra global fetch. Aggregation is graph-local so it fuses into the
// epilogue: acc -> T_lds (bf16) -> skeleton aggregation -> H + atomics stats.
// IN-PLACE safe (H==Ag): block reads only its own 66 rows, all reads drained
// by the epilogue syncthreads before any H write; no cross-block row sharing.
// ACT==0: identity, Ag = external x (dtype per flag).
// ACT==1: BN-ReLU scale/shift applied during reg-staging, Ag internal bf16.
template<int ACT>
__global__ __launch_bounds__(256, 2) void fused_kernel(
    const void* __restrict__ Ag, const u16* __restrict__ Bt,
    const float* __restrict__ fscale, const float* __restrict__ fshift,
    const void* __restrict__ bias, u16* __restrict__ H,
    float* __restrict__ repl, const int* __restrict__ flag)
{
  // K-loop layout: sA = u16[96][32] @ 0 (6 KB; rows 66..95 never staged),
  //                sB = u16[256][32] @ 3072 u16 (16 KB)
  // epilogue layout: Tl = u16[66][264] @ 0 (34,848 B)
  __shared__ __align__(16) u16 smem[17424];
  u16* const sA = smem;
  u16* const sB = smem + 3072;
  const int tid = threadIdx.x;
  const int lane = tid & 63, w = tid >> 6;
  const int gi = w >> 1, h = w & 1;
  const int fr = lane & 15, q = lane >> 4;
  const size_t R0 = (size_t)blockIdx.x * 66;
  const int dtf = *flag;
  const int isbf = (ACT == 0) ? dtf : 1;

  const u16* Ab = (const u16*)Ag;
  const float* Af = (const float*)Ag;

  floatx4 acc[3][8];
#pragma unroll
  for (int t = 0; t < 3; ++t)
#pragma unroll
    for (int j = 0; j < 8; ++j) acc[t][j] = (floatx4){0.f, 0.f, 0.f, 0.f};

  const int r0 = tid >> 2;          // 0..63 (reg staging row)
  const int c8 = (tid & 3) * 8;     // reg staging col group (shorts)
  const int lr = lane >> 2;         // 0..15 (lds-dma row in 16-row group)
  const int lc = (lane & 3) * 8;    // lds-dma col group (shorts)

  for (int kc = 0; kc < 8; ++kc) {
    const int k0 = kc * 32;
    __syncthreads();
    // ---- stage A rows 0..65 of this block's window ----
    if (ACT == 0 && isbf) {
      gload_lds16(Ab + (R0 + w*16 + lr)*256 + k0 + lc, sA + (w*16)*32);
      if (w == 0) {
        size_t rg = R0 + 64 + lr;                 // lanes>=8 clamped for safety
        if (rg >= NN_TOT) rg = NN_TOT - 1;
        if (lane < 8)
          gload_lds16(Ab + rg*256 + k0 + lc, sA + 64*32);
      }
    } else if (ACT == 0) {                        // fp32 input -> bf16
      {
        const float* ap = Af + (R0 + r0)*256 + k0 + c8;
        float4 p0 = *(const float4*)(ap);
        float4 p1 = *(const float4*)(ap + 4);
        u16 ov[8];
        ov[0]=f2bf(p0.x); ov[1]=f2bf(p0.y); ov[2]=f2bf(p0.z); ov[3]=f2bf(p0.w);
        ov[4]=f2bf(p1.x); ov[5]=f2bf(p1.y); ov[6]=f2bf(p1.z); ov[7]=f2bf(p1.w);
        *(uint4*)(sA + r0*32 + c8) = *(const uint4*)ov;
      }
      if (tid < 8) {
        const int r = 64 + (tid >> 2);
        const float* ap = Af + (R0 + r)*256 + k0 + c8;
        float4 p0 = *(const float4*)(ap);
        float4 p1 = *(const float4*)(ap + 4);
        u16 ov[8];
        ov[0]=f2bf(p0.x); ov[1]=f2bf(p0.y); ov[2]=f2bf(p0.z); ov[3]=f2bf(p0.w);
        ov[4]=f2bf(p1.x); ov[5]=f2bf(p1.y); ov[6]=f2bf(p1.z); ov[7]=f2bf(p1.w);
        *(uint4*)(sA + r*32 + c8) = *(const uint4*)ov;
      }
    } else {                                      // ACT==1: bf16 + BN-ReLU
      float scv[8], shv[8];
#pragma unroll
      for (int j = 0; j < 8; ++j) { scv[j] = fscale[k0 + c8 + j]; shv[j] = fshift[k0 + c8 + j]; }
      {
        uint4 pk = *(const uint4*)(Ab + (R0 + r0)*256 + k0 + c8);
        const u16* us = (const u16*)&pk;
        u16 ov[8];
#pragma unroll
        for (int j = 0; j < 8; ++j) {
          float f = bf2f(us[j]);
          f = fmaxf(0.f, fmaf(f, scv[j], shv[j]));
          ov[j] = f2bf(f);
        }
        *(uint4*)(sA + r0*32 + c8) = *(const uint4*)ov;
      }
      if (tid < 8) {
        const int r = 64 + (tid >> 2);
        uint4 pk = *(const uint4*)(Ab + (R0 + r)*256 + k0 + c8);
        const u16* us = (const u16*)&pk;
        u16 ov[8];
#pragma unroll
        for (int j = 0; j < 8; ++j) {
          float f = bf2f(us[j]);
          f = fmaxf(0.f, fmaf(f, scv[j], shv[j]));
          ov[j] = f2bf(f);
        }
        *(uint4*)(sA + r*32 + c8) = *(const uint4*)ov;
      }
    }
    // ---- stage B (full 256 rows x 32 cols) ----
#pragma unroll
    for (int i = 0; i < 4; ++i)
      gload_lds16(Bt + (w*64 + i*16 + lr)*256 + k0 + lc,
                  sB + (w*64 + i*16)*32);
    __syncthreads();

    short8 a[3], b[8];
#pragma unroll
    for (int t = 0; t < 3; ++t)
      a[t] = *(const short8*)(sA + (gi*33 + t*16 + fr)*32 + q*8);
#pragma unroll
    for (int nf = 0; nf < 8; ++nf)
      b[nf] = *(const short8*)(sB + (h*128 + nf*16 + fr)*32 + q*8);
#pragma unroll
    for (int t = 0; t < 3; ++t)
#pragma unroll
      for (int nf = 0; nf < 8; ++nf)
        acc[t][nf] = __builtin_amdgcn_mfma_f32_16x16x32_bf16(a[t], b[nf], acc[t][nf], 0, 0, 0);
  }

  // ---- epilogue 1: T -> LDS (bf16, rows<33 only; garbage rows discarded) ----
  __syncthreads();
  u16* const Tl = smem;     // [66][264]
#pragma unroll
  for (int t = 0; t < 3; ++t)
#pragma unroll
    for (int nf = 0; nf < 8; ++nf)
#pragma unroll
      for (int r = 0; r < 4; ++r) {
        const int row = t*16 + q*4 + r;
        if (row < 33)
          Tl[(gi*33 + row)*264 + h*128 + nf*16 + fr] = f2bf(acc[t][nf][r]);
      }
  __syncthreads();

  // ---- epilogue 2: graph-local skeleton aggregation + bias + stats ----
  // thread -> (graph g2 = tid>>7, column pair 2*cp, 2*cp+1)
  const int g2 = tid >> 7, cp = tid & 127;
  const size_t Gg = (size_t)blockIdx.x*2 + g2;
  float a0[33], a1[33];
#pragma unroll
  for (int d = 0; d < 33; ++d) { a0[d] = 0.f; a1[d] = 0.f; }
#pragma unroll
  for (int s = 0; s < 33; ++s) {
    const unsigned int pk = *(const unsigned int*)(Tl + (g2*33 + s)*264 + cp*2);
    const float v0 = bf2f((u16)(pk & 0xffffu)) * DINV[s];
    const float v1 = bf2f((u16)(pk >> 16)) * DINV[s];
    a0[s] += v0; a1[s] += v1;                    // self loop
#pragma unroll
    for (int i = 0; i < NBCNT[s]; ++i) { a0[NBR[s][i]] += v0; a1[NBR[s][i]] += v1; }
  }
  const float bv0 = ldin(bias, cp*2,     dtf);
  const float bv1 = ldin(bias, cp*2 + 1, dtf);
  float s10 = 0.f, s20 = 0.f, s11 = 0.f, s21 = 0.f;
  u16* hg = H + Gg * (33*256);
#pragma unroll
  for (int d = 0; d < 33; ++d) {
    const float o0 = fmaf(a0[d], DINV[d], bv0);
    const float o1 = fmaf(a1[d], DINV[d], bv1);
    const unsigned int pw = (unsigned int)f2bf(o0) | ((unsigned int)f2bf(o1) << 16);
    *(unsigned int*)(hg + d*256 + cp*2) = pw;
    s10 += o0; s20 += o0*o0; s11 += o1; s21 += o1*o1;
  }
  float* r1p = repl + (Gg & 63)*512;
  atomicAdd(r1p + cp*2,           s10);
  atomicAdd(r1p + cp*2 + 1,       s11);
  atomicAdd(r1p + 256 + cp*2,     s20);
  atomicAdd(r1p + 256 + cp*2 + 1, s21);
}

// ---- finalize BN stats -> scale/shift ----
__global__ __launch_bounds__(256) void statfin_kernel(const float* __restrict__ repl,
    const void* __restrict__ gamma, const void* __restrict__ beta, float* __restrict__ fs,
    const int* __restrict__ flag)
{
  const int c = threadIdx.x;
  const int isbf = *flag;
  float s1 = 0.f, s2 = 0.f;
  for (int r = 0; r < 64; ++r) { s1 += repl[r*512 + c]; s2 += repl[r*512 + 256 + c]; }
  const float inv = 1.f / (float)NN_TOT;
  const float mu = s1 * inv;
  const float var = s2 * inv - mu*mu;
  const float rs = rsqrtf(var + 1e-5f);
  const float sc = rs * ldin(gamma, c, isbf);
  fs[c] = sc;
  fs[256 + c] = ldin(beta, c, isbf) - mu * sc;
}

// ---- fused layer3 + mean-pool + classifier ----
__global__ __launch_bounds__(256) void final_kernel(const u16* __restrict__ H,
    const float* __restrict__ fs, const float* __restrict__ wq,
    const float* __restrict__ bq, void* __restrict__ outp,
    const int* __restrict__ flag)
{
  const int g = blockIdx.x, c = threadIdx.x;
  const int isbf = *flag;
  const float sc = fs[c], sh = fs[256 + c];
  const u16* hg = H + (size_t)g * (33*256);
  float v = 0.f;
#pragma unroll
  for (int s = 0; s < 33; ++s) {
    float a = DINV[s];
#pragma unroll
    for (int i = 0; i < NBCNT[s]; ++i) a += DINV[NBR[s][i]];
    const float w = DINV[s] * a * (1.f/33.f);   // column-sum of Ahat / 33
    float x = bf2f(hg[s*256 + c]);
    x = fmaxf(0.f, fmaf(x, sc, sh));
    v += w * x;
  }
  float p0 = v*wq[c*4+0], p1 = v*wq[c*4+1], p2 = v*wq[c*4+2], p3 = v*wq[c*4+3];
#pragma unroll
  for (int off = 32; off; off >>= 1) {
    p0 += __shfl_xor(p0, off);
    p1 += __shfl_xor(p1, off);
    p2 += __shfl_xor(p2, off);
    p3 += __shfl_xor(p3, off);
  }
  __shared__ float sred[4][4];
  const int lane = c & 63, wid = c >> 6;
  if (lane == 0) { sred[wid][0]=p0; sred[wid][1]=p1; sred[wid][2]=p2; sred[wid][3]=p3; }
  __syncthreads();
  if (c < 4) {
    float r = sred[0][c] + sred[1][c] + sred[2][c] + sred[3][c] + bq[c];
    if (isbf) ((u16*)outp)[(size_t)g*4 + c] = f2bf(r);
    else      ((float*)outp)[(size_t)g*4 + c] = r;
  }
}

extern "C" void kernel_launch(void* const* d_in, const int* in_sizes, int n_in,
                              void* d_out, int out_size, void* d_ws, size_t ws_size,
                              hipStream_t stream)
{
  const void* x   = d_in[0];
  const void* w0  = d_in[1];
  const void* b0  = d_in[2];
  const void* g0  = d_in[3];
  const void* be0 = d_in[4];
  const void* w1  = d_in[5];
  const void* b1  = d_in[6];
  const void* g1  = d_in[7];
  const void* be1 = d_in[8];
  const void* w2  = d_in[9];
  const void* b2  = d_in[10];
  const void* g2  = d_in[11];
  const void* be2 = d_in[12];
  const void* wh  = d_in[13];
  const void* bh  = d_in[14];
  const void* wc  = d_in[15];
  const void* bc  = d_in[16];

  // Workspace: 66.8 MB total.
  char* ws = (char*)d_ws;
  float* wq   = (float*)(ws + 0);          // 1024 f
  float* bq   = (float*)(ws + 4096);       // 4 f
  float* fs   = (float*)(ws + 4608);       // 3 * 512 f
  int*   flag = (int*)  (ws + 12288);      // dtype flag
  float* repl = (float*)(ws + 16384);      // 3 * 64 * 512 f
  u16*   Wt   = (u16*)  (ws + 409600);     // 3 * 65536 bf16
  u16*   A    = (u16*)  (ws + 802816);     // 135168*256 bf16 (ends at 70,008,832)
  (void)in_sizes; (void)n_in; (void)out_size; (void)ws_size;

  detect_kernel<<<1, 256, 0, stream>>>((const u16*)x, flag);
  transpose_kernel<<<48, 256, 0, stream>>>(w0, w1, w2, Wt, flag);
  init_kernel<<<65, 256, 0, stream>>>(wh, bh, wc, bc, wq, bq, repl, flag);

  // layer 0 (gemm + aggregation + stats fused)
  fused_kernel<0><<<2048, 256, 0, stream>>>(x, Wt, nullptr, nullptr, b0, A, repl, flag);
  statfin_kernel<<<1, 256, 0, stream>>>(repl, g0, be0, fs, flag);
  // layer 1 (in-place)
  fused_kernel<1><<<2048, 256, 0, stream>>>(A, Wt + 65536, fs, fs + 256, b1, A, repl + 32768, flag);
  statfin_kernel<<<1, 256, 0, stream>>>(repl + 32768, g1, be1, fs + 512, flag);
  // layer 2 (in-place)
  fused_kernel<1><<<2048, 256, 0, stream>>>(A, Wt + 131072, fs + 512, fs + 768, b2, A, repl + 65536, flag);
  statfin_kernel<<<1, 256, 0, stream>>>(repl + 65536, g2, be2, fs + 1024, flag);
  // layer 3 + pool + classifier (folded)
  final_kernel<<<4096, 256, 0, stream>>>(A, fs + 1024, wq, bq, d_out, flag);
}

// Round 5
// 423.002 us; speedup vs baseline: 1.4102x; 1.0598x over previous
//
#include <hip/hip_runtime.h>

typedef unsigned short u16;
typedef __attribute__((ext_vector_type(8))) short short8;
typedef __attribute__((ext_vector_type(4))) float floatx4;

#define NN_TOT 135168   // 4096 * 33

#define WAITVM(N) asm volatile("s_waitcnt vmcnt(" #N ")" ::: "memory")
#define WAITLGKM0 asm volatile("s_waitcnt lgkmcnt(0)" ::: "memory")

// ---- compile-time skeleton (from SKELETON_EDGES, incl. self-loops) ----
static constexpr int NBCNT[33] = {2,2,2,2,2,2,2,1,1,1,1,3,3,2,2,4,4,2,2,2,2,1,1,3,3,2,2,3,3,2,2,2,2};
static constexpr int NBR[33][4] = {
 {1,4,0,0},{0,2,0,0},{1,3,0,0},{2,7,0,0},{0,5,0,0},{4,6,0,0},{5,8,0,0},
 {3,0,0,0},{6,0,0,0},{10,0,0,0},{9,0,0,0},
 {12,13,23,0},{11,14,24,0},{11,15,0,0},{12,16,0,0},
 {13,17,19,21},{14,18,20,22},
 {15,19,0,0},{16,20,0,0},{15,17,0,0},{16,18,0,0},{15,0,0,0},{16,0,0,0},
 {11,24,25,0},{12,23,26,0},{23,27,0,0},{24,28,0,0},
 {25,29,31,0},{26,30,32,0},{27,31,0,0},{28,32,0,0},{29,27,0,0},{30,28,0,0}};
static constexpr float R2 = 0.70710678f, R3 = 0.57735027f, R4 = 0.5f, R5 = 0.44721360f;
static constexpr float DINV[33] = {R3,R3,R3,R3,R3,R3,R3, R2,R2,R2,R2, R4,R4, R3,R3, R5,R5,
                                   R3,R3,R3,R3, R2,R2, R4,R4, R3,R3, R4,R4, R3,R3,R3,R3};

__device__ __forceinline__ float bf2f(u16 u) {
  unsigned int v = ((unsigned int)u) << 16; float f; __builtin_memcpy(&f, &v, 4); return f;
}
__device__ __forceinline__ u16 f2bf(float f) {
  unsigned int u; __builtin_memcpy(&u, &f, 4);
  return (u16)((u + 0x7fffu + ((u >> 16) & 1u)) >> 16);
}
__device__ __forceinline__ float ldin(const void* p, int i, int isbf) {
  return isbf ? bf2f(((const u16*)p)[i]) : ((const float*)p)[i];
}
__device__ __forceinline__ void gload_lds16(const u16* g, u16* l) {
  __builtin_amdgcn_global_load_lds((const __attribute__((address_space(1))) unsigned int*)g,
                                   (__attribute__((address_space(3))) unsigned int*)l, 16, 0, 0);
}
// swizzled LDS offset (u16 units): row stride 32 u16; 16B chunk XOR'd by row bits
// -> 16 lanes reading 16 consecutive rows at fixed chunk hit 8 banks (2-way = free)
__device__ __forceinline__ int lof(int row, int qq) {
  return row*32 + ((qq ^ ((row >> 1) & 3)) * 8);
}

// ---- dtype detector (unchanged) ----
__global__ __launch_bounds__(256) void detect_kernel(const u16* __restrict__ x,
                                                     int* __restrict__ flag)
{
  __shared__ int cnt[256];
  const int t = threadIdx.x;
  int c = 0;
  for (int j = 0; j < 16; ++j) {
    u16 u = x[(t*16 + j)*2];
    int e = (u >> 7) & 0xFF;
    c += (e >= 118 && e <= 130) ? 1 : 0;
  }
  cnt[t] = c;
  __syncthreads();
  if (t == 0) {
    int s = 0;
    for (int i = 0; i < 256; ++i) s += cnt[i];
    *flag = (s > 2048) ? 1 : 0;   // 1 = bf16 inputs, 0 = fp32 inputs
  }
}

// ---- W transpose + canonicalize to bf16: Wt[n][k] = W[k][n] ----
__global__ __launch_bounds__(256) void transpose_kernel(const void* __restrict__ w0,
    const void* __restrict__ w1, const void* __restrict__ w2, u16* __restrict__ Wt,
    const int* __restrict__ flag)
{
  const int m = blockIdx.x >> 4;
  const int nb = (blockIdx.x & 15) * 16;
  const void* W = m == 0 ? w0 : (m == 1 ? w1 : w2);
  u16* O = Wt + (size_t)m * 65536;
  const int t = threadIdx.x;
  const int lane = t & 63, wv = t >> 6;
  const int isbf = *flag;
  if (isbf) {
    const u16* Wb = (const u16*)W;
#pragma unroll
    for (int nn = 0; nn < 4; ++nn) {
      const int n = nb + nn*4 + wv;
#pragma unroll
      for (int j = 0; j < 4; ++j) {
        const int k = lane + 64*j;
        O[n*256 + k] = Wb[k*256 + n];
      }
    }
  } else {
    const float* Wf = (const float*)W;
#pragma unroll
    for (int nn = 0; nn < 4; ++nn) {
      const int n = nb + nn*4 + wv;
#pragma unroll
      for (int j = 0; j < 4; ++j) {
        const int k = lane + 64*j;
        O[n*256 + k] = f2bf(Wf[k*256 + n]);
      }
    }
  }
}

// ---- init: wq = wh@wc, bq = bh@wc + bc, zero stat replicas ----
__global__ __launch_bounds__(256) void init_kernel(const void* __restrict__ wh,
    const void* __restrict__ bh, const void* __restrict__ wc, const void* __restrict__ bc,
    float* __restrict__ wq, float* __restrict__ bq, float* __restrict__ repl,
    const int* __restrict__ flag)
{
  const int idx = blockIdx.x*256 + threadIdx.x;
  for (int i = idx; i < 3*64*512; i += 65*256) repl[i] = 0.f;
  const int isbf = *flag;
  const int t = threadIdx.x;
  const int lane = t & 63;
  if (blockIdx.x < 64) {
    const int r = blockIdx.x*4 + (t >> 6);    // wq row, one per wave
    float a0=0.f, a1=0.f, a2=0.f, a3=0.f;
#pragma unroll
    for (int j = 0; j < 4; ++j) {
      const int k = lane + 64*j;
      const float w = ldin(wh, r*256 + k, isbf);
      a0 += w*ldin(wc, k*4+0, isbf); a1 += w*ldin(wc, k*4+1, isbf);
      a2 += w*ldin(wc, k*4+2, isbf); a3 += w*ldin(wc, k*4+3, isbf);
    }
#pragma unroll
    for (int off = 32; off; off >>= 1) {
      a0 += __shfl_xor(a0, off); a1 += __shfl_xor(a1, off);
      a2 += __shfl_xor(a2, off); a3 += __shfl_xor(a3, off);
    }
    if (lane == 0) { wq[r*4+0]=a0; wq[r*4+1]=a1; wq[r*4+2]=a2; wq[r*4+3]=a3; }
  } else if (t < 64) {
    float s0=0.f, s1=0.f, s2=0.f, s3=0.f;
#pragma unroll
    for (int j = 0; j < 4; ++j) {
      const int k = lane + 64*j;
      const float b = ldin(bh, k, isbf);
      s0 += b*ldin(wc, k*4+0, isbf); s1 += b*ldin(wc, k*4+1, isbf);
      s2 += b*ldin(wc, k*4+2, isbf); s3 += b*ldin(wc, k*4+3, isbf);
    }
#pragma unroll
    for (int off = 32; off; off >>= 1) {
      s0 += __shfl_xor(s0, off); s1 += __shfl_xor(s1, off);
      s2 += __shfl_xor(s2, off); s3 += __shfl_xor(s3, off);
    }
    if (lane == 0) {
      bq[0] = s0 + ldin(bc, 0, isbf); bq[1] = s1 + ldin(bc, 1, isbf);
      bq[2] = s2 + ldin(bc, 2, isbf); bq[3] = s3 + ldin(bc, 3, isbf);
    }
  }
}

// ---- FUSED layer: H = Ahat @ (act(Ag) @ W) + b, plus BN stats ----
// Geometry as r4: block = 2 graphs (66 rows), wave (gi,h), grid 2048.
// NEW: counted-vmcnt double-buffered K-loop with RAW s_barrier (loads for
// tile k+1 stay in flight across the barrier; vmcnt never drains to 0 in
// the main loop) + chunk-XOR LDS bank swizzle (pre-swizzled global source
// for the DMA path; swizzled ds_write for the reg path; swizzled frag reads).
template<int ACT>
__global__ __launch_bounds__(256, 2) void fused_kernel(
    const void* __restrict__ Ag, const u16* __restrict__ Bt,
    const float* __restrict__ fscale, const float* __restrict__ fshift,
    const void* __restrict__ bias, u16* __restrict__ H,
    float* __restrict__ repl, const int* __restrict__ flag)
{
  // u16 units: sA0 [96*32] @0, sA1 @3072, sB0 [256*32] @6144, sB1 @14336 (total 45056 B)
  // epilogue overlays Tl = u16[66][264] @0 (34848 B)
  __shared__ __align__(16) u16 smem[22528];
  u16* const sA0 = smem;
  u16* const sA1 = smem + 3072;
  u16* const sB0 = smem + 6144;
  u16* const sB1 = smem + 14336;
  const int tid = threadIdx.x;
  const int lane = tid & 63, w = tid >> 6;
  const int gi = w >> 1, h = w & 1;
  const int fr = lane & 15, q = lane >> 4;
  const int lr = lane >> 2, cq = lane & 3;
  const int swz = (lr >> 1) & 3;           // DMA source-chunk xor (row = base16+lr)
  const int r0 = tid >> 2;                 // reg-staging row 0..63
  const int c8 = (tid & 3) * 8;            // reg-staging col group (shorts)
  const size_t R0 = (size_t)blockIdx.x * 66;
  const int dtf = *flag;
  const int isbf = (ACT == 0) ? dtf : 1;

  const u16* Ab = (const u16*)Ag;
  const float* Af = (const float*)Ag;

  floatx4 acc[3][8];
#pragma unroll
  for (int t = 0; t < 3; ++t)
#pragma unroll
    for (int j = 0; j < 8; ++j) acc[t][j] = (floatx4){0.f, 0.f, 0.f, 0.f};

  // ---------------- staging helpers ----------------
  auto issueB = [&](u16* dst, int k0) {
#pragma unroll
    for (int i = 0; i < 4; ++i)
      gload_lds16(Bt + (w*64 + i*16 + lr)*256 + k0 + (cq ^ swz)*8,
                  dst + (w*64 + i*16)*32);
  };
  auto issueA_dma = [&](u16* dst, int k0) {      // ACT0 bf16: rows 0..79 (w0 does 2)
    gload_lds16(Ab + (R0 + w*16 + lr)*256 + k0 + (cq ^ swz)*8, dst + (w*16)*32);
    if (w == 0) {
      size_t rg = R0 + 64 + lr;
      if (rg >= NN_TOT) rg = NN_TOT - 1;         // clamp (garbage rows masked later)
      gload_lds16(Ab + rg*256 + k0 + (cq ^ swz)*8, dst + 64*32);
    }
  };

  uint4 regA, regA2;
  float sc8[8], sh8[8];
  auto issueA_reg = [&](int k0) {                // ACT1: loads only (no waits)
    float4 t0 = *(const float4*)(fscale + k0 + c8);
    float4 t1 = *(const float4*)(fscale + k0 + c8 + 4);
    float4 t2 = *(const float4*)(fshift + k0 + c8);
    float4 t3 = *(const float4*)(fshift + k0 + c8 + 4);
    sc8[0]=t0.x; sc8[1]=t0.y; sc8[2]=t0.z; sc8[3]=t0.w;
    sc8[4]=t1.x; sc8[5]=t1.y; sc8[6]=t1.z; sc8[7]=t1.w;
    sh8[0]=t2.x; sh8[1]=t2.y; sh8[2]=t2.z; sh8[3]=t2.w;
    sh8[4]=t3.x; sh8[5]=t3.y; sh8[6]=t3.z; sh8[7]=t3.w;
    regA = *(const uint4*)(Ab + (R0 + r0)*256 + k0 + c8);
    if (tid >= 248)                               // wave3 extra: rows 64,65
      regA2 = *(const uint4*)(Ab + (R0 + 64 + ((tid - 248) >> 2))*256 + k0 + c8);
  };
  auto writeA = [&](u16* dst) {                   // transform + swizzled ds_write
    {
      const u16* us = (const u16*)&regA;
      u16 ov[8];
#pragma unroll
      for (int j = 0; j < 8; ++j) {
        float f = bf2f(us[j]);
        f = fmaxf(0.f, fmaf(f, sc8[j], sh8[j]));
        ov[j] = f2bf(f);
      }
      *(uint4*)(dst + r0*32 + ((cq ^ ((r0 >> 1) & 3))*8)) = *(const uint4*)ov;
    }
    if (tid >= 248) {
      const int rr = 64 + ((tid - 248) >> 2);
      const u16* us = (const u16*)&regA2;
      u16 ov[8];
#pragma unroll
      for (int j = 0; j < 8; ++j) {
        float f = bf2f(us[j]);
        f = fmaxf(0.f, fmaf(f, sc8[j], sh8[j]));
        ov[j] = f2bf(f);
      }
      *(uint4*)(dst + rr*32 + ((cq ^ ((rr >> 1) & 3))*8)) = *(const uint4*)ov;
    }
  };

  auto compute = [&](const u16* cA, const u16* cB) {
    short8 a[3], b[8];
#pragma unroll
    for (int t = 0; t < 3; ++t)
      a[t] = *(const short8*)(cA + lof(gi*33 + t*16 + fr, q));
#pragma unroll
    for (int nf = 0; nf < 8; ++nf)
      b[nf] = *(const short8*)(cB + lof(h*128 + nf*16 + fr, q));
#pragma unroll
    for (int t = 0; t < 3; ++t)
#pragma unroll
      for (int nf = 0; nf < 8; ++nf)
        acc[t][nf] = __builtin_amdgcn_mfma_f32_16x16x32_bf16(a[t], b[nf], acc[t][nf], 0, 0, 0);
  };

  // ---------------- K loop ----------------
  if (ACT == 0 && !isbf) {
    // fp32 fallback (not hit at runtime: inputs detected bf16). Full-drain style.
    for (int kc = 0; kc < 8; ++kc) {
      const int k0 = kc * 32;
      __syncthreads();
      {
        const float* ap = Af + (R0 + r0)*256 + k0 + c8;
        float4 p0 = *(const float4*)(ap);
        float4 p1 = *(const float4*)(ap + 4);
        u16 ov[8];
        ov[0]=f2bf(p0.x); ov[1]=f2bf(p0.y); ov[2]=f2bf(p0.z); ov[3]=f2bf(p0.w);
        ov[4]=f2bf(p1.x); ov[5]=f2bf(p1.y); ov[6]=f2bf(p1.z); ov[7]=f2bf(p1.w);
        *(uint4*)(sA0 + r0*32 + ((cq ^ ((r0 >> 1) & 3))*8)) = *(const uint4*)ov;
      }
      if (tid < 8) {
        const int rr = 64 + (tid >> 2);
        const float* ap = Af + (R0 + rr)*256 + k0 + c8;
        float4 p0 = *(const float4*)(ap);
        float4 p1 = *(const float4*)(ap + 4);
        u16 ov[8];
        ov[0]=f2bf(p0.x); ov[1]=f2bf(p0.y); ov[2]=f2bf(p0.z); ov[3]=f2bf(p0.w);
        ov[4]=f2bf(p1.x); ov[5]=f2bf(p1.y); ov[6]=f2bf(p1.z); ov[7]=f2bf(p1.w);
        *(uint4*)(sA0 + rr*32 + ((cq ^ ((rr >> 1) & 3))*8)) = *(const uint4*)ov;
      }
      issueB(sB0, k0);
      __syncthreads();            // compiler drains vmcnt+lgkm here (correctness)
      compute(sA0, sB0);
    }
  } else {
    // pipelined path: prologue stages tile 0
    if (ACT == 0) issueA_dma(sA0, 0); else issueA_reg(0);
    issueB(sB0, 0);
    if (ACT == 1) { WAITVM(4); writeA(sA0); WAITLGKM0; }

    for (int kc = 0; kc < 8; ++kc) {
      u16* curA = (kc & 1) ? sA1 : sA0;
      u16* nxtA = (kc & 1) ? sA0 : sA1;
      u16* curB = (kc & 1) ? sB1 : sB0;
      u16* nxtB = (kc & 1) ? sB0 : sB1;
      if (kc < 7) {
        if (ACT == 0) issueA_dma(nxtA, (kc + 1) * 32);
        else          issueA_reg((kc + 1) * 32);
        issueB(nxtB, (kc + 1) * 32);
      }
      // consume-wait: leave exactly tile-(k+1)'s loads in flight
      if (kc < 7) {
        if (ACT == 0) { if (w == 0) { WAITVM(6); } else { WAITVM(5); } }
        else          { if (w == 3) { WAITVM(10); } else { WAITVM(9); } }
      } else { WAITVM(0); }
      __builtin_amdgcn_sched_barrier(0);
      __builtin_amdgcn_s_barrier();      // RAW barrier: no implicit drain

      compute(curA, curB);

      if (ACT == 1 && kc < 7) { WAITVM(4); writeA(nxtA); }
      WAITLGKM0;                         // ds_writes visible before next barrier
    }
  }

  // ---- epilogue 1: T -> LDS (bf16, rows<33 only; garbage rows discarded) ----
  __syncthreads();
  u16* const Tl = smem;     // [66][264]
#pragma unroll
  for (int t = 0; t < 3; ++t)
#pragma unroll
    for (int nf = 0; nf < 8; ++nf)
#pragma unroll
      for (int r = 0; r < 4; ++r) {
        const int row = t*16 + q*4 + r;
        if (row < 33)
          Tl[(gi*33 + row)*264 + h*128 + nf*16 + fr] = f2bf(acc[t][nf][r]);
      }
  __syncthreads();

  // ---- epilogue 2: graph-local skeleton aggregation + bias + stats ----
  const int g2 = tid >> 7, cp = tid & 127;
  const size_t Gg = (size_t)blockIdx.x*2 + g2;
  float a0[33], a1[33];
#pragma unroll
  for (int d = 0; d < 33; ++d) { a0[d] = 0.f; a1[d] = 0.f; }
#pragma unroll
  for (int s = 0; s < 33; ++s) {
    const unsigned int pk = *(const unsigned int*)(Tl + (g2*33 + s)*264 + cp*2);
    const float v0 = bf2f((u16)(pk & 0xffffu)) * DINV[s];
    const float v1 = bf2f((u16)(pk >> 16)) * DINV[s];
    a0[s] += v0; a1[s] += v1;                    // self loop
#pragma unroll
    for (int i = 0; i < NBCNT[s]; ++i) { a0[NBR[s][i]] += v0; a1[NBR[s][i]] += v1; }
  }
  const float bv0 = ldin(bias, cp*2,     dtf);
  const float bv1 = ldin(bias, cp*2 + 1, dtf);
  float s10 = 0.f, s20 = 0.f, s11 = 0.f, s21 = 0.f;
  u16* hg = H + Gg * (33*256);
#pragma unroll
  for (int d = 0; d < 33; ++d) {
    const float o0 = fmaf(a0[d], DINV[d], bv0);
    const float o1 = fmaf(a1[d], DINV[d], bv1);
    const unsigned int pw = (unsigned int)f2bf(o0) | ((unsigned int)f2bf(o1) << 16);
    *(unsigned int*)(hg + d*256 + cp*2) = pw;
    s10 += o0; s20 += o0*o0; s11 += o1; s21 += o1*o1;
  }
  float* r1p = repl + (Gg & 63)*512;
  atomicAdd(r1p + cp*2,           s10);
  atomicAdd(r1p + cp*2 + 1,       s11);
  atomicAdd(r1p + 256 + cp*2,     s20);
  atomicAdd(r1p + 256 + cp*2 + 1, s21);
}

// ---- finalize BN stats -> scale/shift ----
__global__ __launch_bounds__(256) void statfin_kernel(const float* __restrict__ repl,
    const void* __restrict__ gamma, const void* __restrict__ beta, float* __restrict__ fs,
    const int* __restrict__ flag)
{
  const int c = threadIdx.x;
  const int isbf = *flag;
  float s1 = 0.f, s2 = 0.f;
  for (int r = 0; r < 64; ++r) { s1 += repl[r*512 + c]; s2 += repl[r*512 + 256 + c]; }
  const float inv = 1.f / (float)NN_TOT;
  const float mu = s1 * inv;
  const float var = s2 * inv - mu*mu;
  const float rs = rsqrtf(var + 1e-5f);
  const float sc = rs * ldin(gamma, c, isbf);
  fs[c] = sc;
  fs[256 + c] = ldin(beta, c, isbf) - mu * sc;
}

// ---- fused layer3 + mean-pool + classifier ----
__global__ __launch_bounds__(256) void final_kernel(const u16* __restrict__ H,
    const float* __restrict__ fs, const float* __restrict__ wq,
    const float* __restrict__ bq, void* __restrict__ outp,
    const int* __restrict__ flag)
{
  const int g = blockIdx.x, c = threadIdx.x;
  const int isbf = *flag;
  const float sc = fs[c], sh = fs[256 + c];
  const u16* hg = H + (size_t)g * (33*256);
  float v = 0.f;
#pragma unroll
  for (int s = 0; s < 33; ++s) {
    float a = DINV[s];
#pragma unroll
    for (int i = 0; i < NBCNT[s]; ++i) a += DINV[NBR[s][i]];
    const float w = DINV[s] * a * (1.f/33.f);   // column-sum of Ahat / 33
    float x = bf2f(hg[s*256 + c]);
    x = fmaxf(0.f, fmaf(x, sc, sh));
    v += w * x;
  }
  float p0 = v*wq[c*4+0], p1 = v*wq[c*4+1], p2 = v*wq[c*4+2], p3 = v*wq[c*4+3];
#pragma unroll
  for (int off = 32; off; off >>= 1) {
    p0 += __shfl_xor(p0, off);
    p1 += __shfl_xor(p1, off);
    p2 += __shfl_xor(p2, off);
    p3 += __shfl_xor(p3, off);
  }
  __shared__ float sred[4][4];
  const int lane = c & 63, wid = c >> 6;
  if (lane == 0) { sred[wid][0]=p0; sred[wid][1]=p1; sred[wid][2]=p2; sred[wid][3]=p3; }
  __syncthreads();
  if (c < 4) {
    float r = sred[0][c] + sred[1][c] + sred[2][c] + sred[3][c] + bq[c];
    if (isbf) ((u16*)outp)[(size_t)g*4 + c] = f2bf(r);
    else      ((float*)outp)[(size_t)g*4 + c] = r;
  }
}

extern "C" void kernel_launch(void* const* d_in, const int* in_sizes, int n_in,
                              void* d_out, int out_size, void* d_ws, size_t ws_size,
                              hipStream_t stream)
{
  const void* x   = d_in[0];
  const void* w0  = d_in[1];
  const void* b0  = d_in[2];
  const void* g0  = d_in[3];
  const void* be0 = d_in[4];
  const void* w1  = d_in[5];
  const void* b1  = d_in[6];
  const void* g1  = d_in[7];
  const void* be1 = d_in[8];
  const void* w2  = d_in[9];
  const void* b2  = d_in[10];
  const void* g2  = d_in[11];
  const void* be2 = d_in[12];
  const void* wh  = d_in[13];
  const void* bh  = d_in[14];
  const void* wc  = d_in[15];
  const void* bc  = d_in[16];

  // Workspace: 66.8 MB total.
  char* ws = (char*)d_ws;
  float* wq   = (float*)(ws + 0);          // 1024 f
  float* bq   = (float*)(ws + 4096);       // 4 f
  float* fs   = (float*)(ws + 4608);       // 3 * 512 f
  int*   flag = (int*)  (ws + 12288);      // dtype flag
  float* repl = (float*)(ws + 16384);      // 3 * 64 * 512 f
  u16*   Wt   = (u16*)  (ws + 409600);     // 3 * 65536 bf16
  u16*   A    = (u16*)  (ws + 802816);     // 135168*256 bf16 (ends at 70,008,832)
  (void)in_sizes; (void)n_in; (void)out_size; (void)ws_size;

  detect_kernel<<<1, 256, 0, stream>>>((const u16*)x, flag);
  transpose_kernel<<<48, 256, 0, stream>>>(w0, w1, w2, Wt, flag);
  init_kernel<<<65, 256, 0, stream>>>(wh, bh, wc, bc, wq, bq, repl, flag);

  // layer 0 (gemm + aggregation + stats fused)
  fused_kernel<0><<<2048, 256, 0, stream>>>(x, Wt, nullptr, nullptr, b0, A, repl, flag);
  statfin_kernel<<<1, 256, 0, stream>>>(repl, g0, be0, fs, flag);
  // layer 1 (in-place)
  fused_kernel<1><<<2048, 256, 0, stream>>>(A, Wt + 65536, fs, fs + 256, b1, A, repl + 32768, flag);
  statfin_kernel<<<1, 256, 0, stream>>>(repl + 32768, g1, be1, fs + 512, flag);
  // layer 2 (in-place)
  fused_kernel<1><<<2048, 256, 0, stream>>>(A, Wt + 131072, fs + 512, fs + 768, b2, A, repl + 65536, flag);
  statfin_kernel<<<1, 256, 0, stream>>>(repl + 65536, g2, be2, fs + 1024, flag);
  // layer 3 + pool + classifier (folded)
  final_kernel<<<4096, 256, 0, stream>>>(A, fs + 1024, wq, bq, d_out, flag);
}